// Round 1
// baseline (63.689 us; speedup 1.0000x reference)
//
#include <hip/hip_runtime.h>

// RACNN crop+mask+resize fused kernel.
// images: (64, 3, 448, 448) f32, locs: (64, 3) f32 -> out: (64, 3, 224, 224) f32
// out[b,c,r,q] = bilinear(masked, src_r(b,r), src_q(b,q)) with
//   masked[b,c,i,j] = images[b,c,i,j] * mrow(i) * mcol(j)
// mask/src params derived from locs exactly as the JAX reference.

#define B_N 64
#define C_N 3
#define S_N 448
#define O_N 224

__device__ __forceinline__ float sigm(float x) {
    // jax.nn.sigmoid(x) = 1/(1+exp(-x)); fp32, loose 9e-2 threshold -> __expf ok
    return 1.0f / (1.0f + __expf(-x));
}

__global__ __launch_bounds__(256) void racnn_crop_resize(
    const float* __restrict__ images,
    const float* __restrict__ locs,
    float* __restrict__ out,
    int total) {
    int idx = blockIdx.x * blockDim.x + threadIdx.x;
    if (idx >= total) return;

    int q = idx % O_N;
    int r = (idx / O_N) % O_N;
    int c = (idx / (O_N * O_N)) % C_N;
    int b = idx / (O_N * O_N * C_N);

    const float fS = (float)S_N;

    // --- per-batch box params (match reference clip/floor/where order) ---
    float tx = locs[b * 3 + 0];
    float ty = locs[b * 3 + 1];
    float tl = locs[b * 3 + 2];
    tl = fminf(fmaxf(tl, fS / 3.0f), fS * (2.0f / 3.0f));
    tx = fminf(fmaxf(tx, tl), fS - tl);
    ty = fminf(fmaxf(ty, tl), fS - tl);

    float w_off = fmaxf(floorf(tx - tl), 0.0f);
    float w_end = (tx + tl < fS) ? floorf(tx + tl) : fS;
    float h_off = fmaxf(floorf(ty - tl), 0.0f);
    float h_end = (ty + tl < fS) ? floorf(ty + tl) : fS;

    float Lw = w_end - w_off;
    float Lh = h_end - h_off;

    // axis_src: off + r * (L - 1) / (OUT - 1)
    float src_r = w_off + (float)r * (Lw - 1.0f) / (float)(O_N - 1);
    float src_q = h_off + (float)q * (Lh - 1.0f) / (float)(O_N - 1);

    // interp indices (reference: i0 = clip(floor(src),0,S-1); i1 = clip(i0+1,0,S-1); fr = src - i0)
    float f0r = fminf(fmaxf(floorf(src_r), 0.0f), fS - 1.0f);
    int i0r = (int)f0r;
    int i1r = min(i0r + 1, S_N - 1);
    float frr = src_r - f0r;

    float f0q = fminf(fmaxf(floorf(src_q), 0.0f), fS - 1.0f);
    int i0q = (int)f0q;
    int i1q = min(i0q + 1, S_N - 1);
    float frq = src_q - f0q;

    // masks at the gathered indices (mrow -> axis 2 / row index, mcol -> axis 3 / col index)
    float mr0 = sigm(10.0f * ((float)i0r - w_off)) - sigm(10.0f * ((float)i0r - w_end));
    float mr1 = sigm(10.0f * ((float)i1r - w_off)) - sigm(10.0f * ((float)i1r - w_end));
    float mq0 = sigm(10.0f * ((float)i0q - h_off)) - sigm(10.0f * ((float)i0q - h_end));
    float mq1 = sigm(10.0f * ((float)i1q - h_off)) - sigm(10.0f * ((float)i1q - h_end));

    const float* img = images + (size_t)(b * C_N + c) * (S_N * S_N);
    float v00 = img[i0r * S_N + i0q] * mr0 * mq0;
    float v01 = img[i0r * S_N + i1q] * mr0 * mq1;
    float v10 = img[i1r * S_N + i0q] * mr1 * mq0;
    float v11 = img[i1r * S_N + i1q] * mr1 * mq1;

    // reference order: interp axis 2 (rows) first, then axis 3 (cols)
    float t0 = v00 * (1.0f - frr) + v10 * frr;  // at col i0q
    float t1 = v01 * (1.0f - frr) + v11 * frr;  // at col i1q
    float o = t0 * (1.0f - frq) + t1 * frq;

    out[idx] = o;
}

extern "C" void kernel_launch(void* const* d_in, const int* in_sizes, int n_in,
                              void* d_out, int out_size, void* d_ws, size_t ws_size,
                              hipStream_t stream) {
    const float* images = (const float*)d_in[0];
    const float* locs   = (const float*)d_in[1];
    float* out = (float*)d_out;

    int total = B_N * C_N * O_N * O_N;  // 9,633,792
    int block = 256;
    int grid = (total + block - 1) / block;
    racnn_crop_resize<<<grid, block, 0, stream>>>(images, locs, out, total);
}

// Round 2
// 38.075 us; speedup vs baseline: 1.6727x; 1.6727x over previous
//
#include <hip/hip_runtime.h>

// RACNN crop+mask+resize fused kernel, LDS row-staging version.
// images: (64, 3, 448, 448) f32, locs: (64, 3) f32 -> out: (64, 3, 224, 224) f32
//
// One block per (b, r) output row, covering all 3 channels.
// Row-axis (axis 2) interp params are block-uniform; the two source rows are
// pre-combined into LDS:  comb[c][j] = img[i0r][j]*mr0*(1-frr) + img[i1r][j]*mr1*frr
// so each output pixel needs only 2 LDS gathers + column mask/lerp:
//   out = comb[i0q]*mq0*(1-frq) + comb[i1q]*mq1*frq
// Exactly the reference computation modulo FP reassociation.

#define B_N 64
#define C_N 3
#define S_N 448
#define O_N 224
#define BLOCK 256

__device__ __forceinline__ float sigm(float x) {
    return 1.0f / (1.0f + __expf(-x));
}

__global__ __launch_bounds__(BLOCK) void racnn_crop_resize(
    const float* __restrict__ images,
    const float* __restrict__ locs,
    float* __restrict__ out) {
    __shared__ float comb[C_N][S_N];  // 5376 B

    const int r = blockIdx.x;   // output row (axis 2)
    const int b = blockIdx.y;   // batch
    const int tid = threadIdx.x;

    const float fS = (float)S_N;

    // --- per-batch box params (match reference clip/floor/where order) ---
    float tx = locs[b * 3 + 0];
    float ty = locs[b * 3 + 1];
    float tl = locs[b * 3 + 2];
    tl = fminf(fmaxf(tl, fS / 3.0f), fS * (2.0f / 3.0f));
    tx = fminf(fmaxf(tx, tl), fS - tl);
    ty = fminf(fmaxf(ty, tl), fS - tl);

    float w_off = fmaxf(floorf(tx - tl), 0.0f);
    float w_end = (tx + tl < fS) ? floorf(tx + tl) : fS;
    float h_off = fmaxf(floorf(ty - tl), 0.0f);
    float h_end = (ty + tl < fS) ? floorf(ty + tl) : fS;

    // --- row (axis-2) interp params: uniform across the block ---
    float src_r = w_off + (float)r * (w_end - w_off - 1.0f) * (1.0f / (float)(O_N - 1));
    float f0r = fminf(fmaxf(floorf(src_r), 0.0f), fS - 1.0f);
    int i0r = (int)f0r;
    int i1r = min(i0r + 1, S_N - 1);
    float frr = src_r - f0r;
    float mr0 = sigm(10.0f * (f0r - w_off)) - sigm(10.0f * (f0r - w_end));
    float mr1 = sigm(10.0f * ((float)i1r - w_off)) - sigm(10.0f * ((float)i1r - w_end));
    float A  = mr0 * (1.0f - frr);
    float Bw = mr1 * frr;

    // --- gathered column range (h_off/h_end are integral) ---
    int col_lo = (int)h_off;                 // >= 0
    int col_hi = min((int)h_end, S_N - 1);   // i1q never exceeds this
    int W = col_hi - col_lo + 1;

    // --- stage combined rows into LDS (coalesced unit-stride loads) ---
    const size_t plane = (size_t)S_N * S_N;
    const float* base = images + (size_t)b * C_N * plane;
#pragma unroll
    for (int c = 0; c < C_N; ++c) {
        const float* p0 = base + c * plane + (size_t)i0r * S_N;
        const float* p1 = base + c * plane + (size_t)i1r * S_N;
        for (int j = col_lo + tid; j <= col_hi; j += BLOCK) {
            comb[c][j - col_lo] = p0[j] * A + p1[j] * Bw;
        }
    }
    __syncthreads();

    // --- column (axis-3) interp + mask, one output pixel per thread, 3 channels ---
    if (tid < O_N) {
        const int q = tid;
        float src_q = h_off + (float)q * (h_end - h_off - 1.0f) * (1.0f / (float)(O_N - 1));
        float f0q = fminf(fmaxf(floorf(src_q), 0.0f), fS - 1.0f);
        int i0q = (int)f0q;
        int i1q = min(i0q + 1, S_N - 1);
        float frq = src_q - f0q;
        float mq0 = sigm(10.0f * (f0q - h_off)) - sigm(10.0f * (f0q - h_end));
        float mq1 = sigm(10.0f * ((float)i1q - h_off)) - sigm(10.0f * ((float)i1q - h_end));

        int x0 = min(max(i0q - col_lo, 0), W - 1);
        int x1 = min(max(i1q - col_lo, 0), W - 1);
        float wa = mq0 * (1.0f - frq);
        float wb = mq1 * frq;

#pragma unroll
        for (int c = 0; c < C_N; ++c) {
            float o = comb[c][x0] * wa + comb[c][x1] * wb;
            out[(((size_t)b * C_N + c) * O_N + r) * O_N + q] = o;
        }
    }
}

extern "C" void kernel_launch(void* const* d_in, const int* in_sizes, int n_in,
                              void* d_out, int out_size, void* d_ws, size_t ws_size,
                              hipStream_t stream) {
    const float* images = (const float*)d_in[0];
    const float* locs   = (const float*)d_in[1];
    float* out = (float*)d_out;

    dim3 grid(O_N, B_N);   // (224 rows, 64 batches)
    racnn_crop_resize<<<grid, BLOCK, 0, stream>>>(images, locs, out);
}